// Round 6
// baseline (115.081 us; speedup 1.0000x reference)
//
#include <hip/hip_runtime.h>
#include <hip/hip_fp16.h>
#include <cstdint>
#include <cstddef>

// z = soft_thresh(Toeplitz(v) @ x + W2 @ y, beta) -- complex, N=1024, M=256, B=1024
// Real embedding: C[1024][2048] = A'[1024][2560] @ B'[2560][2048] (layouts R0-R5).
// Output = Re(z) only: [1024,1024] f32 (R4 finding).
//
// R24: back to the R13 embedding structure (Gauss reverted: R22/R23 showed it
// trades A-staging up for MFMA down, and MFMA is not binding). ONE change vs
// R13: 512 threads/block (8 waves = 2x2 spatial x 2-way K-split) instead of
// 256. Identical tile (64x64), LDS (64KB dbuf), per-iter traffic, swizzle,
// 2-deep prefetch, 1 barrier/iter. Waves/CU 8 -> 16 (4/SIMD) to fill the
// per-iteration latency quantum that R19/R23 showed is the binding term.
// Small 16KB LDS 2-way K-reduce + fused soft-threshold epilogue.

#define K_DIM 2560
#define BETA_F 0.01f
#define EPS_F  1e-12f

typedef __attribute__((ext_vector_type(8))) _Float16 half8;
typedef __attribute__((ext_vector_type(4))) _Float16 half4;
typedef __attribute__((ext_vector_type(4))) float   floatx4;

__device__ alignas(16) _Float16 g_Ap[1024 * K_DIM];      // 5 MB
__device__ alignas(16) _Float16 g_Bt[2048 * K_DIM];      // 10 MB

// ---------------- prep (merged): build A' and B' -----------------------------
__global__ __launch_bounds__(256) void build_all(
    const float* __restrict__ v_re, const float* __restrict__ v_im,
    const float* __restrict__ W2_re, const float* __restrict__ W2_im,
    const float* __restrict__ x_re, const float* __restrict__ x_im,
    const float* __restrict__ y_re, const float* __restrict__ y_im)
{
    const int bx = blockIdx.x;
    if (bx < 1280) {
        int t = bx * 256 + threadIdx.x;
        int i  = t / 320;
        int c  = t - i * 320;
        int kp = c * 8;                        // segment-aligned
        half8 h;
        if (kp < 1024) {
#pragma unroll
            for (int j = 0; j < 8; ++j) h[j] = (_Float16)v_re[1023 + i - kp - j];
        } else if (kp < 1280) {
            const float* s = W2_re + i * 256 + (kp - 1024);
#pragma unroll
            for (int j = 0; j < 8; ++j) h[j] = (_Float16)s[j];
        } else if (kp < 2304) {
            int k2 = kp - 1280;
#pragma unroll
            for (int j = 0; j < 8; ++j) h[j] = (_Float16)v_im[1023 + i - k2 - j];
        } else {
            const float* s = W2_im + i * 256 + (kp - 2304);
#pragma unroll
            for (int j = 0; j < 8; ++j) h[j] = (_Float16)s[j];
        }
        *reinterpret_cast<half8*>(g_Ap + (size_t)i * K_DIM + kp) = h;
        return;
    }
    __shared__ float lre[32][33];
    __shared__ float lim[32][33];
    int idx = bx - 1280;                       // 0..1279
    int bk  = idx % 40;
    int by  = idx / 40;
    const float* sre = (bk < 32) ? x_re : y_re;
    const float* sim = (bk < 32) ? x_im : y_im;
    int kb   = (bk < 32) ? bk : (bk - 32);
    int koff = (bk < 32) ? 0 : 1024;
    int k0 = kb * 32;
    int n0 = by * 32;
    int tid = threadIdx.x;
    {   // float4-vectorized transpose staging
        int kk  = tid >> 3;                    // 0..31
        int tx4 = (tid & 7) * 4;
        const floatx4 re4 = *reinterpret_cast<const floatx4*>(
            sre + (size_t)(k0 + kk) * 1024 + n0 + tx4);
        const floatx4 im4 = *reinterpret_cast<const floatx4*>(
            sim + (size_t)(k0 + kk) * 1024 + n0 + tx4);
#pragma unroll
        for (int j = 0; j < 4; ++j) {
            lre[kk][tx4 + j] = re4[j];
            lim[kk][tx4 + j] = im4[j];
        }
    }
    __syncthreads();
    int lane_n = tid >> 3;
    int kq     = (tid & 7) * 4;
    half4 hre, him, hmim;
#pragma unroll
    for (int j = 0; j < 4; ++j) {
        float re = lre[kq + j][lane_n];
        float im = lim[kq + j][lane_n];
        hre[j]  = (_Float16)re;
        him[j]  = (_Float16)im;
        hmim[j] = (_Float16)(-im);
    }
    int n = n0 + lane_n;
    size_t kk2 = (size_t)koff + k0 + kq;
    _Float16* r0 = g_Bt + (size_t)(2 * n)     * K_DIM;
    _Float16* r1 = g_Bt + (size_t)(2 * n + 1) * K_DIM;
    *reinterpret_cast<half4*>(r0 + kk2)        = hre;
    *reinterpret_cast<half4*>(r0 + kk2 + 1280) = hmim;
    *reinterpret_cast<half4*>(r1 + kk2)        = him;
    *reinterpret_cast<half4*>(r1 + kk2 + 1280) = hre;
}

// ---------------- non-split GEMM + fused soft-threshold, BK=128 --------------
// 64x64 tile, BK=128 (4 ksub x 32k), 512 blocks (2/CU), 512 threads = 8 waves:
// (wm,wn) 2x2 spatial quadrants (32x32) x kh 2-way K-split (ksub pair).
// Dbuf LDS (32KB/buf, 1 barrier/iter), 2-deep register prefetch, XOR swizzle.
// 16 waves/CU (4/SIMD). 2-way cross-wave K-reduce (16KB LDS) in epilogue.
__global__ __launch_bounds__(512, 4) void gemm_fused(float* __restrict__ out,
                                                     int out_n)
{
    __shared__ __align__(16) char smem[65536];   // As[2][4][64][64B] | Bs same

    const int tid  = threadIdx.x;
    const int lane = tid & 63;
    const int w    = tid >> 6;          // 0..7
    const int wn   = w & 1;
    const int wm   = (w >> 1) & 1;
    const int kh   = w >> 2;            // K-half: ksub pair {2kh, 2kh+1}

    const int bid = blockIdx.x;          // 0..511
    const int xcd = bid & 7;             // round-robin -> XCD; 8x8 super-tile
    const int t   = bid >> 3;            // 0..63
    const int mi0 = ((xcd & 1) * 8 + (t & 7)) * 64;       // 0..960
    const int ni0 = ((xcd >> 1) * 8 + (t >> 3)) * 64;     // 0..1984

    floatx4 acc[2][2];
#pragma unroll
    for (int a = 0; a < 2; ++a)
#pragma unroll
        for (int b = 0; b < 2; ++b) acc[a][b] = (floatx4)0.0f;

    // staging: 512 thr x 4 chunks (2A + 2B). Thread -> (ks0, rS, jj); covers
    // ksub ks0 and ks0+2. LDS slot (rS, jj^s0) -- same involution as R13.
    const int ks0 = tid >> 8;                // 0..1
    const int rS  = (tid & 255) >> 2;        // 0..63
    const int jj  = tid & 3;
    const int s0  = ((rS & 15) >> 1) & 3;
    char* asW = smem          + ks0 * 4096 + rS * 64 + ((jj ^ s0) * 16); // +buf*16384 (+8192 for ks0+2)
    char* bsW = smem + 32768  + ks0 * 4096 + rS * 64 + ((jj ^ s0) * 16);
    const _Float16* gA = g_Ap + (size_t)(mi0 + rS) * K_DIM + ks0 * 32 + jj * 8;
    const _Float16* gB = g_Bt + (size_t)(ni0 + rS) * K_DIM + ks0 * 32 + jj * 8;

    const int rowA = lane & 15;
    const int q    = lane >> 4;
    const int coff = (q ^ ((rowA >> 1) & 3)) * 16;

    const int NIT = K_DIM / 128;         // 20

    // 2-deep prefetch sets: set[(kt+1)&1] holds slab kt+1 during iter kt
    half8 sA[2][2], sB[2][2];            // [set][chunk: ks0 / ks0+2]

    {   // prologue: slab 0 -> LDS buf 0 (via temps); slab 1 -> set[1]
        half8 tA[2], tB[2];
#pragma unroll
        for (int c = 0; c < 2; ++c) {
            tA[c] = *reinterpret_cast<const half8*>(gA + c * 64);
            tB[c] = *reinterpret_cast<const half8*>(gB + c * 64);
        }
#pragma unroll
        for (int c = 0; c < 2; ++c) {
            sA[1][c] = *reinterpret_cast<const half8*>(gA + 128 + c * 64);
            sB[1][c] = *reinterpret_cast<const half8*>(gB + 128 + c * 64);
        }
#pragma unroll
        for (int c = 0; c < 2; ++c) {
            *reinterpret_cast<half8*>(asW + c * 8192) = tA[c];
            *reinterpret_cast<half8*>(bsW + c * 8192) = tB[c];
        }
    }
    __syncthreads();

#pragma unroll 2
    for (int kt = 0; kt < NIT; ++kt) {
        const int cur = kt & 1;
        const int nxt = cur ^ 1;
        if (kt + 2 < NIT) {              // issue slab kt+2 into set[cur]
            const _Float16* ga = gA + (size_t)(kt + 2) * 128;
            const _Float16* gb = gB + (size_t)(kt + 2) * 128;
#pragma unroll
            for (int c = 0; c < 2; ++c) {
                sA[cur][c] = *reinterpret_cast<const half8*>(ga + c * 64);
                sB[cur][c] = *reinterpret_cast<const half8*>(gb + c * 64);
            }
        }
        // compute: this wave's ksub pair {2kh, 2kh+1}, 32x32 quadrant
        const char* Ab = smem         + cur * 16384 + kh * 8192;
        const char* Bb = smem + 32768 + cur * 16384 + kh * 8192;
#pragma unroll
        for (int ks2 = 0; ks2 < 2; ++ks2) {
            half8 af[2], bf[2];
#pragma unroll
            for (int mi = 0; mi < 2; ++mi)
                af[mi] = *reinterpret_cast<const half8*>(
                    Ab + ks2 * 4096 + (wm * 32 + mi * 16 + rowA) * 64 + coff);
#pragma unroll
            for (int ni = 0; ni < 2; ++ni)
                bf[ni] = *reinterpret_cast<const half8*>(
                    Bb + ks2 * 4096 + (wn * 32 + ni * 16 + rowA) * 64 + coff);
#pragma unroll
            for (int mi = 0; mi < 2; ++mi)
#pragma unroll
                for (int ni = 0; ni < 2; ++ni)
                    acc[mi][ni] = __builtin_amdgcn_mfma_f32_16x16x32_f16(
                        af[mi], bf[ni], acc[mi][ni], 0, 0, 0);
        }
        if (kt + 1 < NIT) {              // store slab kt+1 (loaded >=1 iter ago)
            char* aw = asW + nxt * 16384;
            char* bw = bsW + nxt * 16384;
#pragma unroll
            for (int c = 0; c < 2; ++c) {
                *reinterpret_cast<half8*>(aw + c * 8192) = sA[nxt][c];
                *reinterpret_cast<half8*>(bw + c * 8192) = sB[nxt][c];
            }
        }
        __syncthreads();                 // single barrier per iter
    }

    // ---- 2-way cross-wave K-reduce (16KB, reuses smem) + soft-threshold -----
    float* L = (float*)smem;
    if (kh == 1) {
        const int w4 = w - 4;            // 0..3 == partner (wm,wn)
#pragma unroll
        for (int mi = 0; mi < 2; ++mi)
#pragma unroll
            for (int ni = 0; ni < 2; ++ni)
#pragma unroll
                for (int r = 0; r < 4; ++r)
                    L[(((w4 * 2 + mi) * 2 + ni) * 4 + r) * 64 + lane]
                        = acc[mi][ni][r];
    }
    __syncthreads();
    if (kh == 0) {
        // C/D frag map: col=lane&15, row=(lane>>4)*4+r; lane^1 = re/im partner.
        const int colL  = lane & 15;
        const int rquad = (lane >> 4) * 4;
#pragma unroll
        for (int mi = 0; mi < 2; ++mi)
#pragma unroll
            for (int ni = 0; ni < 2; ++ni)
#pragma unroll
                for (int r = 0; r < 4; ++r) {
                    float c = acc[mi][ni][r]
                        + L[(((w * 2 + mi) * 2 + ni) * 4 + r) * 64 + lane];
                    float p = __shfl_xor(c, 1, 64);
                    float mag = sqrtf(c * c + p * p);
                    float s = fmaxf(mag - BETA_F, 0.0f) / fmaxf(mag, EPS_F);
                    int row = mi0 + wm * 32 + mi * 16 + rquad + r;
                    int col = ni0 + wn * 32 + ni * 16 + colL;   // C' col
                    if ((col & 1) == 0) {                        // even = Re
                        size_t idx = (size_t)row * 1024 + (col >> 1);
                        if (idx < (size_t)out_n) out[idx] = c * s;
                    }
                }
    }
}

// ---------------- launcher ---------------------------------------------------
extern "C" void kernel_launch(void* const* d_in, const int* in_sizes, int n_in,
                              void* d_out, int out_size, void* d_ws, size_t ws_size,
                              hipStream_t stream) {
    (void)d_ws; (void)ws_size; (void)in_sizes; (void)n_in;
    const float* v_re  = (const float*)d_in[0];
    const float* v_im  = (const float*)d_in[1];
    const float* W2_re = (const float*)d_in[2];
    const float* W2_im = (const float*)d_in[3];
    const float* x_re  = (const float*)d_in[4];
    const float* x_im  = (const float*)d_in[5];
    const float* y_re  = (const float*)d_in[6];
    const float* y_im  = (const float*)d_in[7];
    float* out = (float*)d_out;

    build_all<<<2560, 256, 0, stream>>>(v_re, v_im, W2_re, W2_im,
                                        x_re, x_im, y_re, y_im);
    gemm_fused<<<512, 512, 0, stream>>>(out, out_size);
}